// Round 5
// baseline (230.255 us; speedup 1.0000x reference)
//
#include <hip/hip_runtime.h>

// Problem constants (match reference)
#define B_ 4
#define N_ 16384
#define M_ 128
#define C_ 128
#define S_ 512
#define ROW_ 131           // 3 + C floats per pooled row
#define NCHUNK_ 256        // 64-point chunks per box (N_/64)
#define TILE_ 128          // unique rows staged in LDS per box
#define LSTR_ 136          // swizzled LDS row stride (floats)
#define KBOX_ 4            // boxes per wave in mask phase

typedef float f4_t __attribute__((ext_vector_type(4)));

// Swizzled LDS address: for a fixed element-within-float4 slot, consecutive
// lanes (col += 4) land on consecutive banks -> conflict-free ds_read_b32.
// Injective for col in [0,131): (col&3)*34 + (col>>2) <= 3*34+32 = 134 < 136.
__device__ __forceinline__ int swz(int j, int col) {
    return j * LSTR_ + (col & 3) * 34 + (col >> 2);
}

// ---------------------------------------------------------------------------
// R13: FUSED mask+pool. One 256-thread block per box (512 blocks total).
// Mask phase keeps R7's KBOX=4 point-reuse: block g's 4 waves are gwaves
// 4g..4g+3, all belonging to box-group g>>2 (segments 4(g&3)..4(g&3)+3),
// each wave testing 1024 register-resident points against 4 boxes.
// Handshake: cluster {g&~3..g|3} produces the 16 mask words of group g>>2;
// after device fence each block sets its bit in ready[g>>2]; consumers spin
// for all 4 bits, then run the proven R9/R11 pool body for box bm = g.
// Monotone-bit flag: poisoned ready in a rocprof replay can only pass early
// (counters slightly off), never hang. Grid 512 = 2 blocks/CU (LDS-capped)
// -> all blocks co-resident -> producer always runs -> no deadlock.
// ws = masks 1 MB + ready 512 B (R12 lesson: big ws costs ~+24 µs/iter in
// harness re-poison).
// ---------------------------------------------------------------------------
__global__ __launch_bounds__(256) void fused_kernel(
    const float* __restrict__ points,        // (B, N, 3)
    const float* __restrict__ feats,         // (B, N, C)
    const float* __restrict__ boxes,         // (B*M, 7)
    unsigned long long* __restrict__ masks,  // (B*M, NCHUNK_)
    int* __restrict__ ready,                 // (B*M/KBOX_,)
    float* __restrict__ out,                 // (B, M, S, 131)
    float* __restrict__ flags_out)           // (B*M,)
{
    const int g    = blockIdx.x;
    const int tid  = threadIdx.x;
    const int w    = tid >> 6;
    const int lane = tid & 63;
    const int k    = g >> 2;                 // cluster / box-group id

    __shared__ int   s_wsum[4];
    __shared__ int   s_idx[S_];
    __shared__ int   jtab[S_ + 1];
    __shared__ float srow[TILE_ * LSTR_];

    // ================= mask phase (verbatim R7 logic, gwave = 4g+w) ========
    {
        const int gwave = g * 4 + w;
        const int grp   = gwave >> 4;        // == g>>2 for all 4 waves
        const int seg   = gwave & 15;
        const int bm0   = grp * KBOX_;
        const int b     = bm0 >> 7;

        const float* pb = points + (size_t)b * N_ * 3;
        float px[16], py[16], pz[16];
        #pragma unroll
        for (int kk = 0; kk < 16; ++kk) {
            const int i = (seg * 16 + kk) * 64 + lane;
            px[kk] = pb[i*3+0]; py[kk] = pb[i*3+1]; pz[kk] = pb[i*3+2];
        }

        for (int kb = 0; kb < KBOX_; ++kb) {
            const int bm = bm0 + kb;
            const float* bx = boxes + bm * 7;
            const float cx = bx[0], cy = bx[1], czb = bx[2];
            const float dx = bx[3], dy = bx[4], dzv = bx[5], rz = bx[6];
            // fp32 reference semantics: no FMA contraction; trig via double
            const float cz   = __fadd_rn(czb, __fmul_rn(0.5f, dzv));
            const float cosa = (float)cos(-(double)rz);
            const float sina = (float)sin(-(double)rz);
            const float hdx = 0.5f * dx, hdy = 0.5f * dy, hdz = 0.5f * dzv;

            #pragma unroll
            for (int kk = 0; kk < 16; ++kk) {
                const float sx = __fsub_rn(px[kk], cx);
                const float sy = __fsub_rn(py[kk], cy);
                const float lx = __fsub_rn(__fmul_rn(sx, cosa), __fmul_rn(sy, sina));
                const float ly = __fadd_rn(__fmul_rn(sx, sina), __fmul_rn(sy, cosa));
                const bool pred = (fabsf(__fsub_rn(pz[kk], cz)) <= hdz) &&
                                  (lx > -hdx) && (lx < hdx) &&
                                  (ly > -hdy) && (ly < hdy);
                const unsigned long long m = __ballot(pred);
                if (lane == 0) masks[(size_t)bm * NCHUNK_ + seg * 16 + kk] = m;
            }
        }
    }

    // ================= handshake ==========================================
    __syncthreads();                         // block's 4 segment-waves done
    if (tid == 0) {
        __threadfence();                     // device-scope release of masks
        atomicOr(&ready[k], 1 << (g & 3));
        while ((__hip_atomic_load(&ready[k], __ATOMIC_ACQUIRE,
                                  __HIP_MEMORY_SCOPE_AGENT) & 15) != 15)
            __builtin_amdgcn_s_sleep(8);
    }
    __syncthreads();                         // all threads see cluster done
    __threadfence();                         // invalidate L1 before mask reads

    // ================= pool phase (R9 body, box bm = g) ====================
    const int bm = g;
    const int b  = bm >> 7;

    const unsigned long long m0 = masks[(size_t)bm * NCHUNK_ + tid];
    const int c = __popcll(m0);

    int incl = c;
    #pragma unroll
    for (int d = 1; d < 64; d <<= 1) {
        const int t = __shfl_up(incl, d, 64);
        if (lane >= d) incl += t;
    }
    if (lane == 63) s_wsum[w] = incl;
    __syncthreads();
    const int w0 = s_wsum[0], w1 = s_wsum[1], w2 = s_wsum[2], w3 = s_wsum[3];
    const int woff  = (w > 0 ? w0 : 0) + (w > 1 ? w1 : 0) + (w > 2 ? w2 : 0);
    const int total = w0 + w1 + w2 + w3;
    int pos = incl - c + woff;               // exclusive prefix (ordered)

    if (c > 0 && pos < S_) {
        unsigned long long m = m0;
        while (m && pos < S_) {
            const int bit = __ffsll((unsigned long long)m) - 1;
            m &= m - 1;
            s_idx[pos++] = tid * 64 + bit;
        }
    }

    const int cnt_eff = total < S_ ? total : S_;
    const int denom   = cnt_eff > 0 ? cnt_eff : 1;
    for (int s = tid; s <= S_; s += 256)
        jtab[s] = (s < S_) ? (int)((unsigned)s % (unsigned)denom) : 0;
    __syncthreads();                         // s_idx + jtab ready

    const int T = cnt_eff < TILE_ ? cnt_eff : TILE_;
    if (total == 0) {
        if (tid < LSTR_) srow[tid] = 0.0f;   // row 0 zeros (j is always 0)
    } else {
        const int nf4 = T * 32;              // 32 float4s of features per row
        for (int t = tid; t < nf4; t += 256) {
            const int u = t >> 5, q = t & 31;
            const size_t pbase = (size_t)b * N_ + (unsigned)s_idx[u];
            const f4_t v = *(const f4_t*)(feats + pbase * C_ + q * 4);
            #pragma unroll
            for (int jj = 0; jj < 4; ++jj)
                srow[swz(u, 3 + 4 * q + jj)] = v[jj];   // <=2-way: free
        }
        for (int t = tid; t < T * 3; t += 256) {
            const int u = t / 3, kk = t - u * 3;
            const size_t pbase = (size_t)b * N_ + (unsigned)s_idx[u];
            srow[swz(u, kk)] = points[pbase * 3 + kk];
        }
    }
    __syncthreads();

    // --- stream output: 16768 float4s = 64 strides of 256 + tail 384 -------
    float* ob = out + (size_t)bm * (S_ * ROW_);
    if (cnt_eff <= TILE_) {
        #pragma unroll 1
        for (int bt = 0; bt < 8; ++bt) {
            f4_t v[8];
            #pragma unroll
            for (int u = 0; u < 8; ++u) {
                const int e = 4 * (tid + (bt * 8 + u) * 256);
                const unsigned s0 = (unsigned)e / (unsigned)ROW_;  // magic-mul
                const int col0 = e - (int)s0 * ROW_;
                const int ja = jtab[s0], jb = jtab[s0 + 1];
                #pragma unroll
                for (int jj = 0; jj < 4; ++jj) {
                    int col = col0 + jj;
                    const bool cross = col >= ROW_;
                    col = cross ? col - ROW_ : col;
                    const int j = cross ? jb : ja;
                    v[u][jj] = srow[swz(j, col)];   // stride-1 banks: no conflict
                }
            }
            #pragma unroll
            for (int u = 0; u < 8; ++u) {
                const int e = 4 * (tid + (bt * 8 + u) * 256);
                *(f4_t*)(ob + e) = v[u];     // 8 back-to-back stores in flight
            }
        }
        for (int f = 16384 + tid; f < 16768; f += 256) {   // tail 384
            const int e = 4 * f;
            const unsigned s0 = (unsigned)e / (unsigned)ROW_;
            const int col0 = e - (int)s0 * ROW_;
            const int ja = jtab[s0], jb = jtab[s0 + 1];
            f4_t v;
            #pragma unroll
            for (int jj = 0; jj < 4; ++jj) {
                int col = col0 + jj;
                const bool cross = col >= ROW_;
                col = cross ? col - ROW_ : col;
                const int j = cross ? jb : ja;
                v[jj] = srow[swz(j, col)];
            }
            *(f4_t*)(ob + e) = v;
        }
    } else {
        // rare path: some rows not staged -> per-element fallback to global
        for (int f = tid; f < (S_ * ROW_) / 4; f += 256) {
            const int e = 4 * f;
            const unsigned s0 = (unsigned)e / (unsigned)ROW_;
            const int col0 = e - (int)s0 * ROW_;
            f4_t v;
            #pragma unroll
            for (int jj = 0; jj < 4; ++jj) {
                int col = col0 + jj;
                unsigned s = s0;
                if (col >= ROW_) { col -= ROW_; ++s; }
                const int j = jtab[s];
                float val;
                if (j < TILE_) {
                    val = srow[swz(j, col)];
                } else {
                    const size_t pbase = (size_t)b * N_ + (unsigned)s_idx[j];
                    val = (col < 3) ? points[pbase * 3 + col]
                                    : feats[pbase * C_ + (col - 3)];
                }
                v[jj] = val;
            }
            *(f4_t*)(ob + e) = v;
        }
    }
    if (tid == 0) flags_out[bm] = (total == 0) ? 1.0f : 0.0f;
}

extern "C" void kernel_launch(void* const* d_in, const int* in_sizes, int n_in,
                              void* d_out, int out_size, void* d_ws, size_t ws_size,
                              hipStream_t stream) {
    const float* points = (const float*)d_in[0];   // (B, N, 3)
    const float* feats  = (const float*)d_in[1];   // (B, N, C)
    const float* boxes  = (const float*)d_in[2];   // (B, M, 7)
    float* out = (float*)d_out;

    char* ws = (char*)d_ws;
    unsigned long long* masks = (unsigned long long*)ws;      // 1 MB
    int* ready = (int*)(ws + (size_t)B_ * M_ * NCHUNK_ * 8);  // 512 B

    float* flags = out + (size_t)B_ * M_ * S_ * ROW_;

    // zero the handshake flags (tiny; keeps ws re-poison cost unchanged)
    hipMemsetAsync(ready, 0, (B_ * M_ / KBOX_) * sizeof(int), stream);
    // fused mask+pool: one 256-thread block per box; 2 blocks/CU, all resident
    fused_kernel<<<B_ * M_, 256, 0, stream>>>(
        points, feats, boxes, masks, ready, out, flags);
}

// Round 6
// 176.789 us; speedup vs baseline: 1.3024x; 1.3024x over previous
//
#include <hip/hip_runtime.h>

// Problem constants (match reference)
#define B_ 4
#define N_ 16384
#define M_ 128
#define C_ 128
#define S_ 512
#define ROW_ 131           // 3 + C floats per pooled row
#define NCHUNK_ 256        // 64-point chunks per box (N_/64)
#define TILE_ 128          // unique rows staged in LDS per box
#define LSTR_ 136          // swizzled LDS row stride (floats)

typedef float f4_t __attribute__((ext_vector_type(4)));

// Swizzled LDS address: for a fixed element-within-float4 slot, consecutive
// lanes (col += 4) land on consecutive banks -> conflict-free ds_read_b32.
// Injective for col in [0,131): (col&3)*34 + (col>>2) <= 3*34+32 = 134 < 136.
__device__ __forceinline__ int swz(int j, int col) {
    return j * LSTR_ + (col & 3) * 34 + (col >> 2);
}

// ---------------------------------------------------------------------------
// R14: fence-free fusion. One 512-thread block per box; the block computes
// its own box's 256 mask words IN-BLOCK (8 waves x 32 chunks, coalesced
// 768B point loads, ballot -> LDS), then runs the proven R11 pool body.
// Rationale: R13 showed cross-block handshake costs ~20 us in L2 fences
// (non-coherent XCD L2s, G16); but per-box points are 196 KB and L2-hot,
// so per-box re-sweep costs ~3 us aggregate — the old KBOX=4 HBM reuse is
// irrelevant once points are cached. Kills: mask dispatch + gap, masks'
// global round-trip, and ALL workspace (ws re-poison -> 0).
// ---------------------------------------------------------------------------
__global__ __launch_bounds__(512, 4) void fused_kernel(
    const float* __restrict__ points,        // (B, N, 3)
    const float* __restrict__ feats,         // (B, N, C)
    const float* __restrict__ boxes,         // (B*M, 7)
    float* __restrict__ out,                 // (B, M, S, 131)
    float* __restrict__ flags_out)           // (B*M,)
{
    const int bm   = blockIdx.x;
    const int b    = bm >> 7;
    const int tid  = threadIdx.x;
    const int w    = tid >> 6;
    const int lane = tid & 63;

    __shared__ unsigned long long mlds[NCHUNK_];
    __shared__ int   s_wsum[4];
    __shared__ int   s_idx[S_];
    __shared__ int   jtab[S_ + 1];           // +1: streaming reads jtab[s0+1]
    __shared__ float srow[TILE_ * LSTR_];

    // ---- box parameters (wave-uniform; trig once per wave) ----------------
    const float* bx = boxes + bm * 7;
    const float cx = bx[0], cy = bx[1], czb = bx[2];
    const float dx = bx[3], dy = bx[4], dzv = bx[5], rz = bx[6];
    // fp32 reference semantics: no FMA contraction; trig via double->fp32
    const float cz   = __fadd_rn(czb, __fmul_rn(0.5f, dzv));
    const float cosa = (float)cos(-(double)rz);
    const float sina = (float)sin(-(double)rz);
    const float hdx = 0.5f * dx, hdy = 0.5f * dy, hdz = 0.5f * dzv;

    // ---- in-block mask sweep: wave w owns chunks [w*32, w*32+32) ----------
    const float* pb = points + (size_t)b * N_ * 3;
    #pragma unroll 4
    for (int cc = 0; cc < 32; ++cc) {
        const int ch = w * 32 + cc;
        const int i  = ch * 64 + lane;       // coalesced: 768B span per wave
        const float x = pb[i*3+0], y = pb[i*3+1], z = pb[i*3+2];
        const float sx = __fsub_rn(x, cx);
        const float sy = __fsub_rn(y, cy);
        const float lx = __fsub_rn(__fmul_rn(sx, cosa), __fmul_rn(sy, sina));
        const float ly = __fadd_rn(__fmul_rn(sx, sina), __fmul_rn(sy, cosa));
        const bool pred = (fabsf(__fsub_rn(z, cz)) <= hdz) &&
                          (lx > -hdx) && (lx < hdx) &&
                          (ly > -hdy) && (ly < hdy);
        const unsigned long long m = __ballot(pred);
        if (lane == 0) mlds[ch] = m;         // bit j == point ch*64+j (order ok)
    }
    __syncthreads();                         // mlds ready

    // ---- scan + expand (R11 logic; m0 now from LDS, not global) -----------
    unsigned long long m0 = 0;
    int c = 0, Ppart = 0;
    if (tid < 256) {
        m0 = mlds[tid];
        c  = __popcll(m0);
        int incl = c;
        #pragma unroll
        for (int d = 1; d < 64; d <<= 1) {
            const int t = __shfl_up(incl, d, 64);
            if (lane >= d) incl += t;
        }
        if (lane == 63) s_wsum[w] = incl;
        Ppart = incl - c;                    // exclusive prefix within wave
    }
    __syncthreads();
    const int w0 = s_wsum[0], w1 = s_wsum[1], w2 = s_wsum[2], w3 = s_wsum[3];
    const int total = w0 + w1 + w2 + w3;

    if (tid < 256 && c > 0) {
        const int woff = (w > 0 ? w0 : 0) + (w > 1 ? w1 : 0) + (w > 2 ? w2 : 0);
        int pos = Ppart + woff;
        if (pos < S_) {
            unsigned long long m = m0;
            while (m && pos < S_) {
                const int bit = __ffsll((unsigned long long)m) - 1;
                m &= m - 1;
                s_idx[pos++] = tid * 64 + bit;
            }
        }
    }

    // ---- wrap-around table (independent of s_idx) -------------------------
    const int cnt_eff = total < S_ ? total : S_;
    const int denom   = cnt_eff > 0 ? cnt_eff : 1;
    for (int s = tid; s <= S_; s += 512)
        jtab[s] = (s < S_) ? (int)((unsigned)s % (unsigned)denom) : 0;
    __syncthreads();                         // s_idx + jtab ready

    // ---- stage unique rows into swizzled LDS ------------------------------
    const int T = cnt_eff < TILE_ ? cnt_eff : TILE_;
    if (total == 0) {
        if (tid < LSTR_) srow[tid] = 0.0f;   // row 0 zeros (j is always 0)
    } else {
        const int nf4 = T * 32;              // 32 float4s of features per row
        for (int t = tid; t < nf4; t += 512) {
            const int u = t >> 5, q = t & 31;
            const size_t pbase = (size_t)b * N_ + (unsigned)s_idx[u];
            const f4_t v = *(const f4_t*)(feats + pbase * C_ + q * 4);
            #pragma unroll
            for (int jj = 0; jj < 4; ++jj)
                srow[swz(u, 3 + 4 * q + jj)] = v[jj];   // <=2-way: free
        }
        for (int t = tid; t < T * 3; t += 512) {
            const int u = t / 3, k = t - u * 3;
            const size_t pbase = (size_t)b * N_ + (unsigned)s_idx[u];
            srow[swz(u, k)] = points[pbase * 3 + k];
        }
    }
    __syncthreads();

    // ---- stream output: 16768 float4s = 32 strides of 512 + tail 384 ------
    float* ob = out + (size_t)bm * (S_ * ROW_);
    if (cnt_eff <= TILE_) {
        // block-uniform fast path: every referenced row is staged
        #pragma unroll 1
        for (int bt = 0; bt < 4; ++bt) {
            f4_t v[8];
            #pragma unroll
            for (int u = 0; u < 8; ++u) {
                const int e = 4 * (tid + (bt * 8 + u) * 512);
                const unsigned s0 = (unsigned)e / (unsigned)ROW_;  // magic-mul
                const int col0 = e - (int)s0 * ROW_;
                const int ja = jtab[s0], jb = jtab[s0 + 1];
                #pragma unroll
                for (int jj = 0; jj < 4; ++jj) {
                    int col = col0 + jj;
                    const bool cross = col >= ROW_;
                    col = cross ? col - ROW_ : col;
                    const int j = cross ? jb : ja;
                    v[u][jj] = srow[swz(j, col)];   // stride-1 banks: no conflict
                }
            }
            #pragma unroll
            for (int u = 0; u < 8; ++u) {
                const int e = 4 * (tid + (bt * 8 + u) * 512);
                *(f4_t*)(ob + e) = v[u];     // 8 back-to-back stores in flight
            }
        }
        if (tid < 384) {                     // tail: f = tid + 16384
            const int e = 4 * (tid + 16384);
            const unsigned s0 = (unsigned)e / (unsigned)ROW_;
            const int col0 = e - (int)s0 * ROW_;
            const int ja = jtab[s0], jb = jtab[s0 + 1];
            f4_t v;
            #pragma unroll
            for (int jj = 0; jj < 4; ++jj) {
                int col = col0 + jj;
                const bool cross = col >= ROW_;
                col = cross ? col - ROW_ : col;
                const int j = cross ? jb : ja;
                v[jj] = srow[swz(j, col)];
            }
            *(f4_t*)(ob + e) = v;
        }
    } else {
        // rare path: some rows not staged -> per-element fallback to global
        for (int f = tid; f < (S_ * ROW_) / 4; f += 512) {
            const int e = 4 * f;
            const unsigned s0 = (unsigned)e / (unsigned)ROW_;
            const int col0 = e - (int)s0 * ROW_;
            f4_t v;
            #pragma unroll
            for (int jj = 0; jj < 4; ++jj) {
                int col = col0 + jj;
                unsigned s = s0;
                if (col >= ROW_) { col -= ROW_; ++s; }
                const int j = jtab[s];
                float val;
                if (j < TILE_) {
                    val = srow[swz(j, col)];
                } else {
                    const size_t pbase = (size_t)b * N_ + (unsigned)s_idx[j];
                    val = (col < 3) ? points[pbase * 3 + col]
                                    : feats[pbase * C_ + (col - 3)];
                }
                v[jj] = val;
            }
            *(f4_t*)(ob + e) = v;
        }
    }
    if (tid == 0) flags_out[bm] = (total == 0) ? 1.0f : 0.0f;
}

extern "C" void kernel_launch(void* const* d_in, const int* in_sizes, int n_in,
                              void* d_out, int out_size, void* d_ws, size_t ws_size,
                              hipStream_t stream) {
    const float* points = (const float*)d_in[0];   // (B, N, 3)
    const float* feats  = (const float*)d_in[1];   // (B, N, C)
    const float* boxes  = (const float*)d_in[2];   // (B, M, 7)
    float* out = (float*)d_out;

    float* flags = out + (size_t)B_ * M_ * S_ * ROW_;

    // Single dispatch: fence-free fused mask+pool, one 512-thread block per
    // box; 2 blocks/CU (LDS-capped), zero workspace.
    fused_kernel<<<B_ * M_, 512, 0, stream>>>(
        points, feats, boxes, out, flags);
}

// Round 7
// 175.806 us; speedup vs baseline: 1.3097x; 1.0056x over previous
//
#include <hip/hip_runtime.h>

// Problem constants (match reference)
#define B_ 4
#define N_ 16384
#define M_ 128
#define C_ 128
#define S_ 512
#define ROW_ 131           // 3 + C floats per pooled row
#define NCHUNK_ 256        // 64-point chunks per box (N_/64)
#define TILE_ 128          // unique rows staged in LDS per box
#define LSTR2_ 132         // linear LDS row stride (floats), 132%32=4
#define KBOX_ 4            // boxes per wave in mask kernel

typedef float f4_t __attribute__((ext_vector_type(4)));

// ---------------------------------------------------------------------------
// Phase A: per-(box, chunk) in-box bitmask via wave ballot. (unchanged, R7)
// ---------------------------------------------------------------------------
__global__ __launch_bounds__(256) void mask_kernel(
    const float* __restrict__ points,        // (B, N, 3)
    const float* __restrict__ boxes,         // (B*M, 7)
    unsigned long long* __restrict__ masks)  // (B*M, NCHUNK_)
{
    const int gwave = blockIdx.x * 4 + (threadIdx.x >> 6);
    const int lane  = threadIdx.x & 63;
    const int grp   = gwave >> 4;            // box-group [0, B*M/KBOX_)
    const int seg   = gwave & 15;            // 16 chunks per segment
    const int bm0   = grp * KBOX_;
    const int b     = bm0 >> 7;              // batch (shared by the 4 boxes)

    const float* pb = points + (size_t)b * N_ * 3;
    float px[16], py[16], pz[16];
    #pragma unroll
    for (int k = 0; k < 16; ++k) {
        const int i = (seg * 16 + k) * 64 + lane;
        px[k] = pb[i*3+0]; py[k] = pb[i*3+1]; pz[k] = pb[i*3+2];
    }

    for (int kb = 0; kb < KBOX_; ++kb) {
        const int bm = bm0 + kb;
        const float* bx = boxes + bm * 7;
        const float cx = bx[0], cy = bx[1], czb = bx[2];
        const float dx = bx[3], dy = bx[4], dzv = bx[5], rz = bx[6];
        // fp32 reference semantics: no FMA contraction; trig via double->fp32
        const float cz   = __fadd_rn(czb, __fmul_rn(0.5f, dzv));
        const float cosa = (float)cos(-(double)rz);
        const float sina = (float)sin(-(double)rz);
        const float hdx = 0.5f * dx, hdy = 0.5f * dy, hdz = 0.5f * dzv;

        #pragma unroll
        for (int k = 0; k < 16; ++k) {
            const float sx = __fsub_rn(px[k], cx);
            const float sy = __fsub_rn(py[k], cy);
            const float lx = __fsub_rn(__fmul_rn(sx, cosa), __fmul_rn(sy, sina));
            const float ly = __fadd_rn(__fmul_rn(sx, sina), __fmul_rn(sy, cosa));
            const bool pred = (fabsf(__fsub_rn(pz[k], cz)) <= hdz) &&
                              (lx > -hdx) && (lx < hdx) &&
                              (ly > -hdy) && (ly < hdy);
            const unsigned long long m = __ballot(pred);
            if (lane == 0) masks[(size_t)bm * NCHUNK_ + seg * 16 + k] = m;
        }
    }
}

// ---------------------------------------------------------------------------
// Resolve + pool — R15: per-ROW streaming.
// Evidence (R13 counters): old per-float4 stitch loop = ~37 VALU + 6 ds_read
// per 16B stored -> ~16 us/CU VALU issue (VALUBusy 15% of 104 us) on a
// dependent div->jtab->swz->ds_read->select chain with only 4 waves/SIMD —
// issue/latency-bound, not store-bound (stores alone = 21.7 us/CU).
// New stream: wave w owns rows s = w+8k; j = s%cnt once per ROW (wave-uniform
// -> SALU); linear srow[j*132+col]; lane l reads cols l,l+64,l+128 (stride-1,
// free) and issues 3 coalesced dword stores. ~7x less VALU, ~8x fewer LDS
// ops per byte. jtab + swizzle deleted. Prologue = proven R11.
// ---------------------------------------------------------------------------
__global__ __launch_bounds__(512, 4) void pool_kernel(
    const float* __restrict__ points,        // (B, N, 3)
    const float* __restrict__ feats,         // (B, N, C)
    const unsigned long long* __restrict__ masks,
    float* __restrict__ out,                 // (B, M, S, 131)
    float* __restrict__ flags_out)           // (B*M,)
{
    const int bm   = blockIdx.x;
    const int b    = bm >> 7;
    const int tid  = threadIdx.x;
    const int w    = tid >> 6;
    const int lane = tid & 63;

    __shared__ int   s_wsum[4];
    __shared__ int   s_idx[S_];
    __shared__ float srow[TILE_ * LSTR2_];   // linear rows, stride 132

    // --- mask words + scan: first 4 waves (256 words) ---
    unsigned long long m0 = 0;
    int c = 0, Ppart = 0;
    if (tid < 256) {
        m0 = masks[(size_t)bm * NCHUNK_ + tid];
        c  = __popcll(m0);
        int incl = c;
        #pragma unroll
        for (int d = 1; d < 64; d <<= 1) {
            const int t = __shfl_up(incl, d, 64);
            if (lane >= d) incl += t;
        }
        if (lane == 63) s_wsum[w] = incl;
        Ppart = incl - c;                    // exclusive prefix within wave
    }
    __syncthreads();
    const int w0 = s_wsum[0], w1 = s_wsum[1], w2 = s_wsum[2], w3 = s_wsum[3];
    const int total = w0 + w1 + w2 + w3;

    // --- expand ordered in-box indices (mask already in register) ---
    if (tid < 256 && c > 0) {
        const int woff = (w > 0 ? w0 : 0) + (w > 1 ? w1 : 0) + (w > 2 ? w2 : 0);
        int pos = Ppart + woff;
        if (pos < S_) {
            unsigned long long m = m0;
            while (m && pos < S_) {
                const int bit = __ffsll((unsigned long long)m) - 1;
                m &= m - 1;
                s_idx[pos++] = tid * 64 + bit;
            }
        }
    }
    __syncthreads();                         // s_idx ready

    const int cnt_eff = total < S_ ? total : S_;
    const int denom   = cnt_eff > 0 ? cnt_eff : 1;

    // --- stage unique rows into linear LDS (stride 132) ---
    const int T = cnt_eff < TILE_ ? cnt_eff : TILE_;
    if (total == 0) {
        if (tid < LSTR2_) srow[tid] = 0.0f;  // row 0 zeros (j is always 0)
    } else {
        const int nf4 = T * 32;              // 32 float4s of features per row
        for (int t = tid; t < nf4; t += 512) {
            const int u = t >> 5, q = t & 31;
            const size_t pbase = (size_t)b * N_ + (unsigned)s_idx[u];
            const f4_t v = *(const f4_t*)(feats + pbase * C_ + q * 4);
            #pragma unroll
            for (int jj = 0; jj < 4; ++jj)
                srow[u * LSTR2_ + 3 + 4 * q + jj] = v[jj];
        }
        for (int t = tid; t < T * 3; t += 512) {
            const int u = t / 3, k = t - u * 3;
            const size_t pbase = (size_t)b * N_ + (unsigned)s_idx[u];
            srow[u * LSTR2_ + k] = points[pbase * 3 + k];
        }
    }
    __syncthreads();                         // srow ready

    // --- per-row stream: wave w owns rows s = w, w+8, ..., w+504 -----------
    float* ob = out + (size_t)bm * (S_ * ROW_);
    if (cnt_eff <= TILE_) {
        // fast path: every referenced row is staged in LDS
        #pragma unroll 2
        for (int k = 0; k < 64; ++k) {
            const int s = w + 8 * k;                       // wave-uniform
            const int j = (int)((unsigned)s % (unsigned)denom);  // SALU mod
            const float* r = srow + j * LSTR2_;
            const float a = r[lane];
            const float d2 = r[64 + lane];
            const float d3 = (lane < 3) ? r[128 + lane] : 0.0f;
            float* orow = ob + s * ROW_;
            orow[lane]      = a;             // 256B coalesced dword store
            orow[64 + lane] = d2;
            if (lane < 3) orow[128 + lane] = d3;
        }
    } else {
        // rare path (cnt > 128): rows beyond TILE_ read directly from global
        #pragma unroll 2
        for (int k = 0; k < 64; ++k) {
            const int s = w + 8 * k;
            const int j = (int)((unsigned)s % (unsigned)denom);
            float a, d2, d3 = 0.0f;
            if (j < TILE_) {
                const float* r = srow + j * LSTR2_;
                a  = r[lane];
                d2 = r[64 + lane];
                if (lane < 3) d3 = r[128 + lane];
            } else {
                const size_t pbase = (size_t)b * N_ + (unsigned)s_idx[j];
                const float* fr = feats + pbase * C_;
                a  = (lane < 3) ? points[pbase * 3 + lane] : fr[lane - 3];
                d2 = fr[61 + lane];          // col 64+lane -> feat (64+lane-3)
                if (lane < 3) d3 = fr[125 + lane];
            }
            float* orow = ob + s * ROW_;
            orow[lane]      = a;
            orow[64 + lane] = d2;
            if (lane < 3) orow[128 + lane] = d3;
        }
    }
    if (tid == 0) flags_out[bm] = (total == 0) ? 1.0f : 0.0f;
}

extern "C" void kernel_launch(void* const* d_in, const int* in_sizes, int n_in,
                              void* d_out, int out_size, void* d_ws, size_t ws_size,
                              hipStream_t stream) {
    const float* points = (const float*)d_in[0];   // (B, N, 3)
    const float* feats  = (const float*)d_in[1];   // (B, N, C)
    const float* boxes  = (const float*)d_in[2];   // (B, M, 7)
    float* out = (float*)d_out;

    // Workspace: masks (1 MB)
    unsigned long long* masks = (unsigned long long*)d_ws;

    float* flags = out + (size_t)B_ * M_ * S_ * ROW_;

    // Phase A: (512/KBOX_) box-groups x 16 segments = 2048 waves = 512 blocks
    mask_kernel<<<B_ * M_ * 16 / 4 / KBOX_, 256, 0, stream>>>(
        points, boxes, masks);
    // Resolve + pool: one 512-thread block per box, per-row streaming
    pool_kernel<<<B_ * M_, 512, 0, stream>>>(points, feats, masks, out, flags);
}